// Round 1
// baseline (1372.410 us; speedup 1.0000x reference)
//
#include <hip/hip_runtime.h>
#include <hip/hip_bf16.h>
#include <math.h>

// Problem constants (from reference)
constexpr int N_   = 8192;    // nodes
constexpr int D_   = 256;     // feature dim
constexpr int E_   = 131072;  // edges
constexpr int G_   = 16;      // graphs
constexpr int MN_  = 512;     // max nodes per graph (dense batch)
constexpr int H_   = 8;       // heads
constexpr int DH_  = 32;      // dim per head
constexpr int MAXG_= 512;     // table size

// ---------------- small index kernels ----------------

__global__ void k_deg(const int* __restrict__ src, int* __restrict__ deg) {
    int e = blockIdx.x * 256 + threadIdx.x;
    if (e < E_) atomicAdd(deg + src[e], 1);
}

__global__ void k_counts(const int* __restrict__ batch, int* __restrict__ counts) {
    int n = blockIdx.x * 256 + threadIdx.x;
    if (n < N_) atomicAdd(counts + batch[n], 1);
}

__global__ void k_scan(const int* __restrict__ counts, int* __restrict__ starts) {
    if (threadIdx.x == 0 && blockIdx.x == 0) {
        int acc = 0;
        for (int g = 0; g < G_; ++g) { starts[g] = acc; acc += counts[g]; }
    }
}

__global__ void k_pos(const int* __restrict__ batch, const int* __restrict__ starts,
                      int* __restrict__ pos) {
    int n = blockIdx.x * 256 + threadIdx.x;
    if (n < N_) pos[n] = n - starts[batch[n]];
}

// ---------------- edge scatter-add: x_acc[src[e]] += edge_feature[e] ----------------
// 64 threads per edge, float4 per thread, 4 fp32 atomics.
__global__ void k_scatter_edges(const int* __restrict__ src, const float* __restrict__ ef,
                                float* __restrict__ xacc) {
    int t  = blockIdx.x * 256 + threadIdx.x;
    int e  = t >> 6;
    int c4 = (t & 63) * 4;
    if (e >= E_) return;
    float4 v = *(const float4*)(ef + (size_t)e * D_ + c4);
    float* dst = xacc + (size_t)src[e] * D_ + c4;
    atomicAdd(dst + 0, v.x);
    atomicAdd(dst + 1, v.y);
    atomicAdd(dst + 2, v.z);
    atomicAdd(dst + 3, v.w);
}

// ---------------- build dense batch: dense[batch,pos] = nf + centrality[deg] + x_acc ----------------
__global__ void k_build_dense(const float* __restrict__ nf, const float* __restrict__ cent,
                              const float* __restrict__ xacc, const int* __restrict__ deg,
                              const int* __restrict__ batch, const int* __restrict__ pos,
                              float* __restrict__ dense, int* __restrict__ mask,
                              int* __restrict__ node_for) {
    int t  = blockIdx.x * 256 + threadIdx.x;
    int n  = t >> 6;
    int c4 = (t & 63) * 4;
    if (n >= N_) return;
    int g = batch[n], p = pos[n];
    int row = g * MN_ + p;
    int dg = min(deg[n], MAXG_ - 1);
    float4 a = *(const float4*)(nf   + (size_t)n  * D_ + c4);
    float4 b = *(const float4*)(cent + (size_t)dg * D_ + c4);
    float4 c = *(const float4*)(xacc + (size_t)n  * D_ + c4);
    float4 o;
    o.x = a.x + b.x + c.x; o.y = a.y + b.y + c.y;
    o.z = a.z + b.z + c.z; o.w = a.w + b.w + c.w;
    *(float4*)(dense + (size_t)row * D_ + c4) = o;
    if (c4 == 0) { mask[row] = 1; node_for[row] = n; }
}

// ---------------- simple fp32 GEMM: C[r, :NC] = A[r, :256] @ B[256, NC] ----------------
// One wave per (row, 256-col stripe): A element broadcast, B float4 coalesced.
template<int NC>
__global__ __launch_bounds__(256) void k_gemm(const float* __restrict__ A,
                                              const float* __restrict__ B,
                                              float* __restrict__ C, int nrows) {
    constexpr int TPR = NC / 4;        // threads per row
    constexpr int RPB = 256 / TPR;     // rows per block
    int row = blockIdx.x * RPB + threadIdx.x / TPR;
    int cb  = (threadIdx.x % TPR) * 4;
    if (row >= nrows) return;
    const float* a = A + (size_t)row * 256;
    float4 acc = {0.f, 0.f, 0.f, 0.f};
    for (int k = 0; k < 256; k += 4) {
        float4 av = *(const float4*)(a + k);
        const float* b0 = B + (size_t)k * NC + cb;
        float4 b;
        b = *(const float4*)(b0);
        acc.x += av.x * b.x; acc.y += av.x * b.y; acc.z += av.x * b.z; acc.w += av.x * b.w;
        b = *(const float4*)(b0 + NC);
        acc.x += av.y * b.x; acc.y += av.y * b.y; acc.z += av.y * b.z; acc.w += av.y * b.w;
        b = *(const float4*)(b0 + 2 * NC);
        acc.x += av.z * b.x; acc.y += av.z * b.y; acc.z += av.z * b.z; acc.w += av.z * b.w;
        b = *(const float4*)(b0 + 3 * NC);
        acc.x += av.w * b.x; acc.y += av.w * b.y; acc.z += av.w * b.z; acc.w += av.w * b.w;
    }
    *(float4*)(C + (size_t)row * NC + cb) = acc;
}

// ---------------- attention: one thread per (g, h, i) row, online softmax ----------------
__global__ __launch_bounds__(256) void k_attn(const float* __restrict__ qb,
                                              const float* __restrict__ kvb,
                                              const int* __restrict__ dist,
                                              const float* __restrict__ dist_bias,
                                              const int* __restrict__ mask,
                                              float* __restrict__ ob) {
    // blockIdx.x = g*16 + h*2 + chunk ; i = chunk*256 + threadIdx.x
    int bid = blockIdx.x;
    int g = bid >> 4;
    int h = (bid >> 1) & 7;
    int i = ((bid & 1) << 8) + threadIdx.x;
    const float scale = 0.17677669529663687f;  // 32^-0.5

    const float* qr = qb + (size_t)(g * MN_ + i) * D_ + h * DH_;
    float4 qf[8];
#pragma unroll
    for (int r = 0; r < 8; ++r) qf[r] = *(const float4*)(qr + r * 4);

    const int* drow = dist + (size_t)(g * MN_ + i) * MN_;
    const int* mrow = mask + g * MN_;

    float m = -INFINITY, l = 0.f;
    float4 acc[8];
#pragma unroll
    for (int r = 0; r < 8; ++r) acc[r] = make_float4(0.f, 0.f, 0.f, 0.f);

    for (int j = 0; j < MN_; ++j) {
        if (!mrow[j]) continue;
        const float* kr = kvb + (size_t)(g * MN_ + j) * 512 + h * DH_;
        float s = 0.f;
#pragma unroll
        for (int r = 0; r < 8; ++r) {
            float4 kk = *(const float4*)(kr + r * 4);
            s += qf[r].x * kk.x + qf[r].y * kk.y + qf[r].z * kk.z + qf[r].w * kk.w;
        }
        int dd = min(drow[j], MAXG_ - 1);
        s = s * scale + dist_bias[dd * H_ + h];
        float mnew = fmaxf(m, s);
        float corr = __expf(m - mnew);   // 0 on first valid j (m = -inf)
        float p    = __expf(s - mnew);
        l = l * corr + p;
        const float* vr = kr + 256;
#pragma unroll
        for (int r = 0; r < 8; ++r) {
            float4 vv = *(const float4*)(vr + r * 4);
            acc[r].x = acc[r].x * corr + p * vv.x;
            acc[r].y = acc[r].y * corr + p * vv.y;
            acc[r].z = acc[r].z * corr + p * vv.z;
            acc[r].w = acc[r].w * corr + p * vv.w;
        }
        m = mnew;
    }
    float inv = l > 0.f ? 1.f / l : 0.f;
    float* orow = ob + (size_t)(g * MN_ + i) * D_ + h * DH_;
#pragma unroll
    for (int r = 0; r < 8; ++r) {
        float4 o = make_float4(acc[r].x * inv, acc[r].y * inv, acc[r].z * inv, acc[r].w * inv);
        *(float4*)(orow + r * 4) = o;
    }
}

// ---------------- output projection + ragged unpack + last-graph zeroing ----------------
__global__ __launch_bounds__(256) void k_proj_o(const float* __restrict__ A,
                                                const float* __restrict__ Wo,
                                                const float* __restrict__ bo,
                                                const int* __restrict__ mask,
                                                const int* __restrict__ node_for,
                                                float* __restrict__ out) {
    int row = blockIdx.x * 4 + threadIdx.x / 64;
    int cb  = (threadIdx.x & 63) * 4;
    if (row >= G_ * MN_) return;
    if (!mask[row]) return;           // no node in this slot
    int n = node_for[row];
    int g = row / MN_;
    float4 acc = {0.f, 0.f, 0.f, 0.f};
    if (g != G_ - 1) {                // last graph's outputs are zeroed (reference off-by-one)
        const float* a = A + (size_t)row * 256;
        for (int k = 0; k < 256; k += 4) {
            float4 av = *(const float4*)(a + k);
            const float* b0 = Wo + (size_t)k * 256 + cb;
            float4 b;
            b = *(const float4*)(b0);
            acc.x += av.x * b.x; acc.y += av.x * b.y; acc.z += av.x * b.z; acc.w += av.x * b.w;
            b = *(const float4*)(b0 + 256);
            acc.x += av.y * b.x; acc.y += av.y * b.y; acc.z += av.y * b.z; acc.w += av.y * b.w;
            b = *(const float4*)(b0 + 512);
            acc.x += av.z * b.x; acc.y += av.z * b.y; acc.z += av.z * b.z; acc.w += av.z * b.w;
            b = *(const float4*)(b0 + 768);
            acc.x += av.w * b.x; acc.y += av.w * b.y; acc.z += av.w * b.z; acc.w += av.w * b.w;
        }
        float4 bb = *(const float4*)(bo + cb);
        acc.x += bb.x; acc.y += bb.y; acc.z += bb.z; acc.w += bb.w;
    }
    *(float4*)(out + (size_t)n * 256 + cb) = acc;
}

// ---------------- launch ----------------

extern "C" void kernel_launch(void* const* d_in, const int* in_sizes, int n_in,
                              void* d_out, int out_size, void* d_ws, size_t ws_size,
                              hipStream_t stream) {
    const float* node_feature = (const float*)d_in[0];
    const float* edge_feature = (const float*)d_in[1];
    const float* centrality   = (const float*)d_in[2];
    const float* dist_bias    = (const float*)d_in[3];
    const float* Wq           = (const float*)d_in[4];
    const float* Wkv          = (const float*)d_in[5];
    const float* Wo           = (const float*)d_in[6];
    const float* bo           = (const float*)d_in[7];
    const int*   edge_index   = (const int*)d_in[8];
    const int*   batch        = (const int*)d_in[9];
    const int*   dist         = (const int*)d_in[10];
    float* out = (float*)d_out;

    // workspace layout (~50.5 MB)
    float* x_acc  = (float*)d_ws;                       // N*D
    float* dense  = x_acc + (size_t)N_ * D_;            // G*MN*D == N*D
    float* qbuf   = dense + (size_t)N_ * D_;            // N*D
    float* kvbuf  = qbuf  + (size_t)N_ * D_;            // N*512
    float* obuf   = kvbuf + (size_t)N_ * 512;           // N*D
    int*   deg    = (int*)(obuf + (size_t)N_ * D_);     // N
    int*   maskp  = deg    + N_;                        // G*MN
    int*   counts = maskp  + G_ * MN_;                  // G
    int*   starts = counts + G_;                        // G
    int*   pos    = starts + G_;                        // N
    int*   node_for = pos  + N_;                        // G*MN

    // zero: x_acc + dense (contiguous 16 MB); deg + mask + counts (contiguous)
    hipMemsetAsync(x_acc, 0, (size_t)2 * N_ * D_ * sizeof(float), stream);
    hipMemsetAsync(deg, 0, (size_t)(N_ + G_ * MN_ + G_) * sizeof(int), stream);

    const int* src = edge_index;  // row 0 of (2, E)

    k_deg<<<E_ / 256, 256, 0, stream>>>(src, deg);
    k_counts<<<N_ / 256, 256, 0, stream>>>(batch, counts);
    k_scan<<<1, 64, 0, stream>>>(counts, starts);
    k_pos<<<N_ / 256, 256, 0, stream>>>(batch, starts, pos);
    k_scatter_edges<<<(E_ * 64) / 256, 256, 0, stream>>>(src, edge_feature, x_acc);
    k_build_dense<<<(N_ * 64) / 256, 256, 0, stream>>>(node_feature, centrality, x_acc, deg,
                                                       batch, pos, dense, maskp, node_for);
    k_gemm<256><<<(G_ * MN_) / 4, 256, 0, stream>>>(dense, Wq, qbuf, G_ * MN_);
    k_gemm<512><<<(G_ * MN_) / 2, 256, 0, stream>>>(dense, Wkv, kvbuf, G_ * MN_);
    k_attn<<<G_ * H_ * 2, 256, 0, stream>>>(qbuf, kvbuf, dist, dist_bias, maskp, obuf);
    k_proj_o<<<(G_ * MN_) / 4, 256, 0, stream>>>(obuf, Wo, bo, maskp, node_for, out);
}

// Round 2
// 894.330 us; speedup vs baseline: 1.5346x; 1.5346x over previous
//
#include <hip/hip_runtime.h>
#include <hip/hip_bf16.h>
#include <math.h>

// Problem constants (from reference)
constexpr int N_   = 8192;    // nodes
constexpr int D_   = 256;     // feature dim
constexpr int E_   = 131072;  // edges
constexpr int G_   = 16;      // graphs
constexpr int MN_  = 512;     // max nodes per graph (dense batch)
constexpr int H_   = 8;       // heads
constexpr int DH_  = 32;      // dim per head
constexpr int MAXG_= 512;     // table size

// ---------------- small index kernels ----------------

__global__ void k_deg(const int* __restrict__ src, int* __restrict__ deg) {
    int e = blockIdx.x * 256 + threadIdx.x;
    if (e < E_) atomicAdd(deg + src[e], 1);
}

__global__ void k_counts(const int* __restrict__ batch, int* __restrict__ counts) {
    int n = blockIdx.x * 256 + threadIdx.x;
    if (n < N_) atomicAdd(counts + batch[n], 1);
}

__global__ void k_scan(const int* __restrict__ counts, int* __restrict__ starts) {
    if (threadIdx.x == 0 && blockIdx.x == 0) {
        int acc = 0;
        for (int g = 0; g < G_; ++g) { starts[g] = acc; acc += counts[g]; }
    }
}

__global__ void k_pos(const int* __restrict__ batch, const int* __restrict__ starts,
                      int* __restrict__ pos) {
    int n = blockIdx.x * 256 + threadIdx.x;
    if (n < N_) pos[n] = n - starts[batch[n]];
}

// ---------------- exclusive scan of deg over N nodes (single block) ----------------
__global__ void k_scan_deg(const int* __restrict__ deg, int* __restrict__ offs,
                           int* __restrict__ cursor) {
    __shared__ int tpre[256];
    int t = threadIdx.x;
    int base = t * 32;
    int local[32];
    int s = 0;
#pragma unroll
    for (int k = 0; k < 32; ++k) { local[k] = deg[base + k]; s += local[k]; }
    __shared__ int tsum[256];
    tsum[t] = s;
    __syncthreads();
    if (t == 0) {
        int acc = 0;
        for (int i = 0; i < 256; ++i) { tpre[i] = acc; acc += tsum[i]; }
    }
    __syncthreads();
    int acc = tpre[t];
#pragma unroll
    for (int k = 0; k < 32; ++k) {
        offs[base + k] = acc;
        cursor[base + k] = acc;
        acc += local[k];
    }
}

// ---------------- CSR bucket fill: one int atomic per edge ----------------
__global__ void k_fill_csr(const int* __restrict__ src, int* __restrict__ cursor,
                           int* __restrict__ eids) {
    int e = blockIdx.x * 256 + threadIdx.x;
    if (e < E_) {
        int slot = atomicAdd(cursor + src[e], 1);
        eids[slot] = e;
    }
}

// ---------------- build dense batch, fused edge gather ----------------
// dense[batch,pos] = nf + centrality[min(deg,511)] + sum(edge_feature[eids of n])
__global__ void k_build_dense(const float* __restrict__ nf, const float* __restrict__ cent,
                              const float* __restrict__ ef, const int* __restrict__ deg,
                              const int* __restrict__ offs, const int* __restrict__ eids,
                              const int* __restrict__ batch, const int* __restrict__ pos,
                              float* __restrict__ dense, int* __restrict__ mask,
                              int* __restrict__ node_for) {
    int t  = blockIdx.x * 256 + threadIdx.x;
    int n  = t >> 6;
    int c4 = (t & 63) * 4;
    if (n >= N_) return;
    int g = batch[n], p = pos[n];
    int row = g * MN_ + p;
    int dn = deg[n];
    int dg = min(dn, MAXG_ - 1);
    float4 a = *(const float4*)(nf   + (size_t)n  * D_ + c4);
    float4 b = *(const float4*)(cent + (size_t)dg * D_ + c4);
    float4 o;
    o.x = a.x + b.x; o.y = a.y + b.y; o.z = a.z + b.z; o.w = a.w + b.w;
    int beg = offs[n], end = beg + dn;
    for (int idx = beg; idx < end; ++idx) {
        int e = eids[idx];                    // broadcast across the node's 64 threads
        float4 v = *(const float4*)(ef + (size_t)e * D_ + c4);
        o.x += v.x; o.y += v.y; o.z += v.z; o.w += v.w;
    }
    *(float4*)(dense + (size_t)row * D_ + c4) = o;
    if (c4 == 0) { mask[row] = 1; node_for[row] = n; }
}

// ---------------- simple fp32 GEMM: C[r, :NC] = A[r, :256] @ B[256, NC] ----------------
template<int NC>
__global__ __launch_bounds__(256) void k_gemm(const float* __restrict__ A,
                                              const float* __restrict__ B,
                                              float* __restrict__ C, int nrows) {
    constexpr int TPR = NC / 4;        // threads per row
    constexpr int RPB = 256 / TPR;     // rows per block
    int row = blockIdx.x * RPB + threadIdx.x / TPR;
    int cb  = (threadIdx.x % TPR) * 4;
    if (row >= nrows) return;
    const float* a = A + (size_t)row * 256;
    float4 acc = {0.f, 0.f, 0.f, 0.f};
    for (int k = 0; k < 256; k += 4) {
        float4 av = *(const float4*)(a + k);
        const float* b0 = B + (size_t)k * NC + cb;
        float4 b;
        b = *(const float4*)(b0);
        acc.x += av.x * b.x; acc.y += av.x * b.y; acc.z += av.x * b.z; acc.w += av.x * b.w;
        b = *(const float4*)(b0 + NC);
        acc.x += av.y * b.x; acc.y += av.y * b.y; acc.z += av.y * b.z; acc.w += av.y * b.w;
        b = *(const float4*)(b0 + 2 * NC);
        acc.x += av.z * b.x; acc.y += av.z * b.y; acc.z += av.z * b.z; acc.w += av.z * b.w;
        b = *(const float4*)(b0 + 3 * NC);
        acc.x += av.w * b.x; acc.y += av.w * b.y; acc.z += av.w * b.z; acc.w += av.w * b.w;
    }
    *(float4*)(C + (size_t)row * NC + cb) = acc;
}

// ---------------- attention: 4 threads per (g,h,i) row, online softmax ----------------
// Each thread owns 8 of the 32 head dims; partial q.k reduced via shfl_xor over
// the 4-lane group; softmax state (m, l) replicated within the group.
__global__ __launch_bounds__(256) void k_attn(const float* __restrict__ qb,
                                              const float* __restrict__ kvb,
                                              const int* __restrict__ dist,
                                              const float* __restrict__ dist_bias,
                                              const int* __restrict__ mask,
                                              float* __restrict__ ob) {
    int t   = blockIdx.x * 256 + threadIdx.x;   // 0 .. 4*G*H*MN-1
    int sub = t & 3;                            // dh quarter (8 dims)
    int rid = t >> 2;                           // (g*H + h)*MN + i
    int i   = rid & (MN_ - 1);
    int gh  = rid >> 9;
    int h   = gh & (H_ - 1);
    int g   = gh >> 3;
    const float scale = 0.17677669529663687f;   // 32^-0.5

    const float* qr = qb + (size_t)(g * MN_ + i) * D_ + h * DH_ + sub * 8;
    float4 q0 = *(const float4*)(qr);
    float4 q1 = *(const float4*)(qr + 4);

    const int* drow = dist + ((size_t)g * MN_ + i) * MN_;
    const int* mrow = mask + g * MN_;

    float m = -INFINITY, l = 0.f;
    float4 a0 = make_float4(0.f, 0.f, 0.f, 0.f);
    float4 a1 = make_float4(0.f, 0.f, 0.f, 0.f);

    for (int j = 0; j < MN_; ++j) {
        if (!mrow[j]) continue;
        const float* kr = kvb + (size_t)(g * MN_ + j) * 512 + h * DH_ + sub * 8;
        float4 k0 = *(const float4*)(kr);
        float4 k1 = *(const float4*)(kr + 4);
        float s = q0.x * k0.x + q0.y * k0.y + q0.z * k0.z + q0.w * k0.w
                + q1.x * k1.x + q1.y * k1.y + q1.z * k1.z + q1.w * k1.w;
        s += __shfl_xor(s, 1, 4);
        s += __shfl_xor(s, 2, 4);
        int dd = min(drow[j], MAXG_ - 1);
        s = s * scale + dist_bias[dd * H_ + h];
        float mnew = fmaxf(m, s);
        float corr = __expf(m - mnew);   // 0 on first valid j
        float p    = __expf(s - mnew);
        l = l * corr + p;
        const float* vr = kr + 256;
        float4 v0 = *(const float4*)(vr);
        float4 v1 = *(const float4*)(vr + 4);
        a0.x = a0.x * corr + p * v0.x; a0.y = a0.y * corr + p * v0.y;
        a0.z = a0.z * corr + p * v0.z; a0.w = a0.w * corr + p * v0.w;
        a1.x = a1.x * corr + p * v1.x; a1.y = a1.y * corr + p * v1.y;
        a1.z = a1.z * corr + p * v1.z; a1.w = a1.w * corr + p * v1.w;
        m = mnew;
    }
    float inv = l > 0.f ? 1.f / l : 0.f;
    float* orow = ob + (size_t)(g * MN_ + i) * D_ + h * DH_ + sub * 8;
    *(float4*)(orow)     = make_float4(a0.x * inv, a0.y * inv, a0.z * inv, a0.w * inv);
    *(float4*)(orow + 4) = make_float4(a1.x * inv, a1.y * inv, a1.z * inv, a1.w * inv);
}

// ---------------- output projection + ragged unpack + last-graph zeroing ----------------
__global__ __launch_bounds__(256) void k_proj_o(const float* __restrict__ A,
                                                const float* __restrict__ Wo,
                                                const float* __restrict__ bo,
                                                const int* __restrict__ mask,
                                                const int* __restrict__ node_for,
                                                float* __restrict__ out) {
    int row = blockIdx.x * 4 + threadIdx.x / 64;
    int cb  = (threadIdx.x & 63) * 4;
    if (row >= G_ * MN_) return;
    if (!mask[row]) return;           // no node in this slot
    int n = node_for[row];
    int g = row / MN_;
    float4 acc = {0.f, 0.f, 0.f, 0.f};
    if (g != G_ - 1) {                // last graph's outputs are zeroed (reference off-by-one)
        const float* a = A + (size_t)row * 256;
        for (int k = 0; k < 256; k += 4) {
            float4 av = *(const float4*)(a + k);
            const float* b0 = Wo + (size_t)k * 256 + cb;
            float4 b;
            b = *(const float4*)(b0);
            acc.x += av.x * b.x; acc.y += av.x * b.y; acc.z += av.x * b.z; acc.w += av.x * b.w;
            b = *(const float4*)(b0 + 256);
            acc.x += av.y * b.x; acc.y += av.y * b.y; acc.z += av.y * b.z; acc.w += av.y * b.w;
            b = *(const float4*)(b0 + 512);
            acc.x += av.z * b.x; acc.y += av.z * b.y; acc.z += av.z * b.z; acc.w += av.z * b.w;
            b = *(const float4*)(b0 + 768);
            acc.x += av.w * b.x; acc.y += av.w * b.y; acc.z += av.w * b.z; acc.w += av.w * b.w;
        }
        float4 bb = *(const float4*)(bo + cb);
        acc.x += bb.x; acc.y += bb.y; acc.z += bb.z; acc.w += bb.w;
    }
    *(float4*)(out + (size_t)n * 256 + cb) = acc;
}

// ---------------- launch ----------------

extern "C" void kernel_launch(void* const* d_in, const int* in_sizes, int n_in,
                              void* d_out, int out_size, void* d_ws, size_t ws_size,
                              hipStream_t stream) {
    const float* node_feature = (const float*)d_in[0];
    const float* edge_feature = (const float*)d_in[1];
    const float* centrality   = (const float*)d_in[2];
    const float* dist_bias    = (const float*)d_in[3];
    const float* Wq           = (const float*)d_in[4];
    const float* Wkv          = (const float*)d_in[5];
    const float* Wo           = (const float*)d_in[6];
    const float* bo           = (const float*)d_in[7];
    const int*   edge_index   = (const int*)d_in[8];
    const int*   batch        = (const int*)d_in[9];
    const int*   dist         = (const int*)d_in[10];
    float* out = (float*)d_out;

    // workspace layout (~41 MB)
    float* dense  = (float*)d_ws;                       // N*D   (8 MB)
    float* qbuf   = dense + (size_t)N_ * D_;            // N*D   (8 MB)
    float* kvbuf  = qbuf  + (size_t)N_ * D_;            // N*512 (16 MB)
    float* obuf   = kvbuf + (size_t)N_ * 512;           // N*D   (8 MB)
    int*   deg    = (int*)(obuf + (size_t)N_ * D_);     // N
    int*   maskp  = deg    + N_;                        // G*MN
    int*   counts = maskp  + G_ * MN_;                  // G
    int*   starts = counts + G_;                        // G
    int*   pos    = starts + G_;                        // N
    int*   node_for = pos  + N_;                        // G*MN
    int*   offs   = node_for + G_ * MN_;                // N
    int*   cursor = offs   + N_;                        // N
    int*   eids   = cursor + N_;                        // E

    // zero: deg + mask + counts (contiguous); dense (generic-safety for unfilled slots)
    hipMemsetAsync(deg, 0, (size_t)(N_ + G_ * MN_ + G_) * sizeof(int), stream);
    hipMemsetAsync(dense, 0, (size_t)N_ * D_ * sizeof(float), stream);

    const int* src = edge_index;  // row 0 of (2, E)

    k_deg<<<E_ / 256, 256, 0, stream>>>(src, deg);
    k_counts<<<N_ / 256, 256, 0, stream>>>(batch, counts);
    k_scan<<<1, 64, 0, stream>>>(counts, starts);
    k_pos<<<N_ / 256, 256, 0, stream>>>(batch, starts, pos);
    k_scan_deg<<<1, 256, 0, stream>>>(deg, offs, cursor);
    k_fill_csr<<<E_ / 256, 256, 0, stream>>>(src, cursor, eids);
    k_build_dense<<<(N_ * 64) / 256, 256, 0, stream>>>(node_feature, centrality, edge_feature,
                                                       deg, offs, eids, batch, pos,
                                                       dense, maskp, node_for);
    k_gemm<256><<<(G_ * MN_) / 4, 256, 0, stream>>>(dense, Wq, qbuf, G_ * MN_);
    k_gemm<512><<<(G_ * MN_) / 2, 256, 0, stream>>>(dense, Wkv, kvbuf, G_ * MN_);
    k_attn<<<(4 * G_ * H_ * MN_) / 256, 256, 0, stream>>>(qbuf, kvbuf, dist, dist_bias,
                                                          maskp, obuf);
    k_proj_o<<<(G_ * MN_) / 4, 256, 0, stream>>>(obuf, Wo, bo, maskp, node_for, out);
}

// Round 3
// 295.502 us; speedup vs baseline: 4.6443x; 3.0265x over previous
//
#include <hip/hip_runtime.h>
#include <hip/hip_bf16.h>
#include <math.h>

constexpr int N_   = 8192;
constexpr int D_   = 256;
constexpr int E_   = 131072;
constexpr int G_   = 16;
constexpr int MN_  = 512;
constexpr int H_   = 8;
constexpr int MAXG_= 512;

typedef __attribute__((ext_vector_type(8))) short short8v;   // 8 bf16 (4 VGPR)
typedef __attribute__((ext_vector_type(4))) float f32x4;     // MFMA C/D

// ---- bf16 helpers (RTNE via integer ops; input finite) ----
__device__ inline ushort f2bf(float f) {
    unsigned u = __float_as_uint(f);
    return (ushort)((u + 0x7FFFu + ((u >> 16) & 1u)) >> 16);
}
__device__ inline float bf2f(ushort h) { return __uint_as_float((unsigned)h << 16); }
__device__ inline unsigned cvt_pk_bf16(float lo, float hi) {
    unsigned r;
    asm("v_cvt_pk_bf16_f32 %0, %1, %2" : "=v"(r) : "v"(lo), "v"(hi));
    return r;
}

// ---------------- small index kernels ----------------
__global__ void k_deg(const int* __restrict__ src, int* __restrict__ deg) {
    int e = blockIdx.x * 256 + threadIdx.x;
    if (e < E_) atomicAdd(deg + src[e], 1);
}
__global__ void k_counts(const int* __restrict__ batch, int* __restrict__ counts) {
    int n = blockIdx.x * 256 + threadIdx.x;
    if (n < N_) atomicAdd(counts + batch[n], 1);
}
__global__ void k_scan(const int* __restrict__ counts, int* __restrict__ starts) {
    if (threadIdx.x == 0 && blockIdx.x == 0) {
        int acc = 0;
        for (int g = 0; g < G_; ++g) { starts[g] = acc; acc += counts[g]; }
    }
}
__global__ void k_pos(const int* __restrict__ batch, const int* __restrict__ starts,
                      int* __restrict__ pos) {
    int n = blockIdx.x * 256 + threadIdx.x;
    if (n < N_) pos[n] = n - starts[batch[n]];
}
__global__ void k_scan_deg(const int* __restrict__ deg, int* __restrict__ offs,
                           int* __restrict__ cursor) {
    __shared__ int tpre[256];
    __shared__ int tsum[256];
    int t = threadIdx.x;
    int base = t * 32;
    int local[32];
    int s = 0;
#pragma unroll
    for (int k = 0; k < 32; ++k) { local[k] = deg[base + k]; s += local[k]; }
    tsum[t] = s;
    __syncthreads();
    if (t == 0) {
        int acc = 0;
        for (int i = 0; i < 256; ++i) { tpre[i] = acc; acc += tsum[i]; }
    }
    __syncthreads();
    int acc = tpre[t];
#pragma unroll
    for (int k = 0; k < 32; ++k) {
        offs[base + k] = acc;
        cursor[base + k] = acc;
        acc += local[k];
    }
}
__global__ void k_fill_csr(const int* __restrict__ src, int* __restrict__ cursor,
                           int* __restrict__ eids) {
    int e = blockIdx.x * 256 + threadIdx.x;
    if (e < E_) {
        int slot = atomicAdd(cursor + src[e], 1);
        eids[slot] = e;
    }
}

// ---------------- build dense batch (CSR edge gather fused) ----------------
__global__ void k_build_dense(const float* __restrict__ nf, const float* __restrict__ cent,
                              const float* __restrict__ ef, const int* __restrict__ deg,
                              const int* __restrict__ offs, const int* __restrict__ eids,
                              const int* __restrict__ batch, const int* __restrict__ pos,
                              float* __restrict__ dense) {
    int t  = blockIdx.x * 256 + threadIdx.x;
    int n  = t >> 6;
    int c4 = (t & 63) * 4;
    if (n >= N_) return;
    int g = batch[n], p = pos[n];
    int row = g * MN_ + p;
    int dn = deg[n];
    int dg = min(dn, MAXG_ - 1);
    float4 a = *(const float4*)(nf   + (size_t)n  * D_ + c4);
    float4 b = *(const float4*)(cent + (size_t)dg * D_ + c4);
    float4 o;
    o.x = a.x + b.x; o.y = a.y + b.y; o.z = a.z + b.z; o.w = a.w + b.w;
    int beg = offs[n], end = beg + dn;
    for (int idx = beg; idx < end; ++idx) {
        int e = eids[idx];
        float4 v = *(const float4*)(ef + (size_t)e * D_ + c4);
        o.x += v.x; o.y += v.y; o.z += v.z; o.w += v.w;
    }
    *(float4*)(dense + (size_t)row * D_ + c4) = o;
}

// ---------------- tiled fp32 GEMM: [8192 x 256] @ [256 x NC] ----------------
// MODE 0: float out + bias ; MODE 1: hi/lo bf16 out ; MODE 2: K->hi/lo, V->bf16
template<int NC, int MODE>
__global__ __launch_bounds__(256) void k_gemm_t(const float* __restrict__ A,
        const float* __restrict__ B, const float* __restrict__ bias,
        float* __restrict__ Cf, ushort* __restrict__ Hh, ushort* __restrict__ Ll,
        ushort* __restrict__ Vb) {
    __shared__ float As[64][20];   // padded: broadcast reads 2-way max
    __shared__ float Bs[16][64];
    int t = threadIdx.x;
    int mrow = blockIdx.x * 64;
    int ncol = blockIdx.y * 64;
    int tm = t >> 4, tn = t & 15;
    float acc[4][4] = {};
    for (int kc = 0; kc < 256; kc += 16) {
        {
            int r = t >> 2, k4 = (t & 3) * 4;
            *(float4*)&As[r][k4] = *(const float4*)(A + (size_t)(mrow + r) * 256 + kc + k4);
            int kk = t >> 4, c4 = (t & 15) * 4;
            *(float4*)&Bs[kk][c4] = *(const float4*)(B + (size_t)(kc + kk) * NC + ncol + c4);
        }
        __syncthreads();
#pragma unroll
        for (int k = 0; k < 16; ++k) {
            float4 b4 = *(float4*)&Bs[k][tn * 4];
#pragma unroll
            for (int u = 0; u < 4; ++u) {
                float a = As[tm * 4 + u][k];
                acc[u][0] += a * b4.x; acc[u][1] += a * b4.y;
                acc[u][2] += a * b4.z; acc[u][3] += a * b4.w;
            }
        }
        __syncthreads();
    }
    int row0 = mrow + tm * 4;
    int col0 = ncol + tn * 4;
#pragma unroll
    for (int u = 0; u < 4; ++u) {
        if (MODE == 0) {
            float4 o;
            o.x = acc[u][0] + bias[col0 + 0];
            o.y = acc[u][1] + bias[col0 + 1];
            o.z = acc[u][2] + bias[col0 + 2];
            o.w = acc[u][3] + bias[col0 + 3];
            *(float4*)(Cf + (size_t)(row0 + u) * NC + col0) = o;
        } else if (MODE == 1) {
            ushort4 hh, ll;
            float x;
            x = acc[u][0]; hh.x = f2bf(x); ll.x = f2bf(x - bf2f(hh.x));
            x = acc[u][1]; hh.y = f2bf(x); ll.y = f2bf(x - bf2f(hh.y));
            x = acc[u][2]; hh.z = f2bf(x); ll.z = f2bf(x - bf2f(hh.z));
            x = acc[u][3]; hh.w = f2bf(x); ll.w = f2bf(x - bf2f(hh.w));
            *(ushort4*)(Hh + (size_t)(row0 + u) * 256 + col0) = hh;
            *(ushort4*)(Ll + (size_t)(row0 + u) * 256 + col0) = ll;
        } else {
            if (ncol < 256) {
                ushort4 hh, ll;
                float x;
                x = acc[u][0]; hh.x = f2bf(x); ll.x = f2bf(x - bf2f(hh.x));
                x = acc[u][1]; hh.y = f2bf(x); ll.y = f2bf(x - bf2f(hh.y));
                x = acc[u][2]; hh.z = f2bf(x); ll.z = f2bf(x - bf2f(hh.z));
                x = acc[u][3]; hh.w = f2bf(x); ll.w = f2bf(x - bf2f(hh.w));
                *(ushort4*)(Hh + (size_t)(row0 + u) * 256 + col0) = hh;
                *(ushort4*)(Ll + (size_t)(row0 + u) * 256 + col0) = ll;
            } else {
                ushort4 vv;
                vv.x = f2bf(acc[u][0]); vv.y = f2bf(acc[u][1]);
                vv.z = f2bf(acc[u][2]); vv.w = f2bf(acc[u][3]);
                *(ushort4*)(Vb + (size_t)(row0 + u) * 256 + (col0 - 256)) = vv;
            }
        }
    }
}

// ---------------- V transpose: vbf[8192][256] -> vt[(g*8+h)*32+d][512] ----------------
__global__ __launch_bounds__(256) void k_conv_vt(const ushort* __restrict__ vbf,
                                                 ushort* __restrict__ vt) {
    __shared__ ushort tile[32][36];
    int bx = blockIdx.x;        // 0..255 : 32-row tiles over 8192 rows
    int h  = blockIdx.y;        // 0..7
    int t  = threadIdx.x;
    int r = t >> 3, c4 = (t & 7) * 4;
    *(ushort4*)&tile[r][c4] =
        *(const ushort4*)(vbf + (size_t)(bx * 32 + r) * 256 + h * 32 + c4);
    __syncthreads();
    int d = t >> 3, j4 = (t & 7) * 4;
    ushort4 o;
    o.x = tile[j4 + 0][d]; o.y = tile[j4 + 1][d];
    o.z = tile[j4 + 2][d]; o.w = tile[j4 + 3][d];
    int g = bx >> 4, jb = (bx & 15) * 32;
    *(ushort4*)(vt + ((size_t)(g * 8 + h) * 32 + d) * 512 + jb + j4) = o;
}

// ---------------- MFMA flash attention ----------------
// Per wave: one (g,h) and a 16-row i-tile. S^T via mfma(A=K,B=Q) (hi/lo split),
// online softmax with i = lane&15, PV via mfma(A=P, B=V-chunk).
__global__ __launch_bounds__(256) void k_attn_mfma(
    const ushort* __restrict__ qh, const ushort* __restrict__ qlo,
    const ushort* __restrict__ kh, const ushort* __restrict__ klo,
    const ushort* __restrict__ vt,
    const int* __restrict__ dist, const float* __restrict__ dist_bias,
    const int* __restrict__ counts, float* __restrict__ ob)
{
    int b  = blockIdx.x;
    int gh = b >> 3;                 // g*8 + h
    int g  = gh >> 3, h = gh & 7;
    int w    = threadIdx.x >> 6;
    int lane = threadIdx.x & 63;
    int ib   = (b & 7) * 64 + w * 16;
    int l15  = lane & 15, quad = lane >> 4;
    const float scale = 0.17677669529663687f;

    __shared__ float biasH[512];
    for (int idx = threadIdx.x; idx < 512; idx += 256) biasH[idx] = dist_bias[idx * 8 + h];
    __syncthreads();
    int cnt = counts[g];

    // Q frags (B operand): lane holds Q[ib+l15][quad*8 + t]
    size_t qoff = ((size_t)(g * 512 + ib + l15)) * 256 + h * 32 + quad * 8;
    short8v qfh = *(const short8v*)(qh  + qoff);
    short8v qfl = *(const short8v*)(qlo + qoff);

    float m = -INFINITY, lsum = 0.f;
    f32x4 acc0 = {0.f, 0.f, 0.f, 0.f}, acc1 = {0.f, 0.f, 0.f, 0.f};

    const ushort* vbase = vt + ((size_t)gh * 32) * 512;
    const int* dbase = dist + ((size_t)(g * 512 + ib + l15)) * 512;
    size_t krowb = (size_t)(g * 512);

    for (int jb = 0; jb < 512; jb += 32) {
        float p[8];
        float mx = -INFINITY;
#pragma unroll
        for (int sub = 0; sub < 2; ++sub) {
            int j0 = jb + sub * 16;
            size_t koff = (krowb + j0 + l15) * 256 + h * 32 + quad * 8;
            short8v kfh = *(const short8v*)(kh  + koff);
            short8v kfl = *(const short8v*)(klo + koff);
            f32x4 c = {0.f, 0.f, 0.f, 0.f};
            c = __builtin_amdgcn_mfma_f32_16x16x32_bf16(kfl, qfh, c, 0, 0, 0);
            c = __builtin_amdgcn_mfma_f32_16x16x32_bf16(kfh, qfl, c, 0, 0, 0);
            c = __builtin_amdgcn_mfma_f32_16x16x32_bf16(kfh, qfh, c, 0, 0, 0);
            int4 d4 = *(const int4*)(dbase + j0 + quad * 4);
            const int* dr = (const int*)&d4;
#pragma unroll
            for (int r = 0; r < 4; ++r) {
                int dd = min(dr[r], MAXG_ - 1);
                float s = c[r] * scale + biasH[dd];
                bool valid = (j0 + quad * 4 + r) < cnt;
                s = valid ? s : -1e30f;
                p[sub * 4 + r] = s;
                mx = fmaxf(mx, s);
            }
        }
        mx = fmaxf(mx, __shfl_xor(mx, 16));
        mx = fmaxf(mx, __shfl_xor(mx, 32));
        float mnew = fmaxf(m, mx);
        float corr = __expf(m - mnew);
        m = mnew;
        float psum = 0.f;
#pragma unroll
        for (int u = 0; u < 8; ++u) {
            float pv = (p[u] > -1e29f) ? __expf(p[u] - m) : 0.f;
            p[u] = pv;
            psum += pv;
        }
        psum += __shfl_xor(psum, 16);
        psum += __shfl_xor(psum, 32);
        lsum = lsum * corr + psum;
#pragma unroll
        for (int r = 0; r < 4; ++r) {
            float cr = __shfl(corr, quad * 4 + r);   // lane i holds corr for row i
            acc0[r] *= cr; acc1[r] *= cr;
        }
        // P -> A-frag (lane needs P[i=l15][k=quad*8+t], k rel. to jb)
        unsigned pk0A = cvt_pk_bf16(p[0], p[1]), pk1A = cvt_pk_bf16(p[2], p[3]);
        unsigned pk0B = cvt_pk_bf16(p[4], p[5]), pk1B = cvt_pk_bf16(p[6], p[7]);
        int srcA = l15 + 16 * (2 * (quad & 1));
        int srcB = srcA + 16;
        unsigned w0A = __shfl((int)pk0A, srcA), w1A = __shfl((int)pk1A, srcA);
        unsigned w2A = __shfl((int)pk0A, srcB), w3A = __shfl((int)pk1A, srcB);
        unsigned w0B = __shfl((int)pk0B, srcA), w1B = __shfl((int)pk1B, srcA);
        unsigned w2B = __shfl((int)pk0B, srcB), w3B = __shfl((int)pk1B, srcB);
        bool hiT = (quad >= 2);
        union { unsigned u[4]; short8v s; } pu;
        pu.u[0] = hiT ? w0B : w0A;
        pu.u[1] = hiT ? w1B : w1A;
        pu.u[2] = hiT ? w2B : w2A;
        pu.u[3] = hiT ? w3B : w3A;
        short8v pa = pu.s;
        // V frags: lane holds V[jb+quad*8+t][d = l15 (+16)]
        short8v v0 = *(const short8v*)(vbase + (size_t)l15 * 512 + jb + quad * 8);
        short8v v1 = *(const short8v*)(vbase + (size_t)(l15 + 16) * 512 + jb + quad * 8);
        acc0 = __builtin_amdgcn_mfma_f32_16x16x32_bf16(pa, v0, acc0, 0, 0, 0);
        acc1 = __builtin_amdgcn_mfma_f32_16x16x32_bf16(pa, v1, acc1, 0, 0, 0);
    }
    float inv = lsum > 0.f ? 1.f / lsum : 0.f;
#pragma unroll
    for (int r = 0; r < 4; ++r) {
        float ir = __shfl(inv, quad * 4 + r);
        int i = ib + quad * 4 + r;
        float* orow = ob + ((size_t)(g * 512 + i)) * 256 + h * 32;
        orow[l15]      = acc0[r] * ir;
        orow[l15 + 16] = acc1[r] * ir;
    }
}

// ---------------- ragged unpack + last-graph zeroing ----------------
__global__ void k_unpack(const float* __restrict__ pred, const int* __restrict__ batch,
                         const int* __restrict__ pos, float* __restrict__ out) {
    int t = blockIdx.x * 256 + threadIdx.x;
    int n = t >> 6, c4 = (t & 63) * 4;
    if (n >= N_) return;
    int g = batch[n];
    int row = g * MN_ + pos[n];
    float4 v = make_float4(0.f, 0.f, 0.f, 0.f);
    if (g < G_ - 1) v = *(const float4*)(pred + (size_t)row * 256 + c4);
    *(float4*)(out + (size_t)n * 256 + c4) = v;
}

// ---------------- launch ----------------
extern "C" void kernel_launch(void* const* d_in, const int* in_sizes, int n_in,
                              void* d_out, int out_size, void* d_ws, size_t ws_size,
                              hipStream_t stream) {
    const float* node_feature = (const float*)d_in[0];
    const float* edge_feature = (const float*)d_in[1];
    const float* centrality   = (const float*)d_in[2];
    const float* dist_bias    = (const float*)d_in[3];
    const float* Wq           = (const float*)d_in[4];
    const float* Wkv          = (const float*)d_in[5];
    const float* Wo           = (const float*)d_in[6];
    const float* bo           = (const float*)d_in[7];
    const int*   edge_index   = (const int*)d_in[8];
    const int*   batch        = (const int*)d_in[9];
    const int*   dist         = (const int*)d_in[10];
    float* out = (float*)d_out;

    const size_t ND = (size_t)N_ * D_;   // 2M elements
    float*  dense = (float*)d_ws;            // 8 MB
    float*  obuf  = dense + ND;              // 8 MB
    float*  pred  = obuf + ND;               // 8 MB
    ushort* qh    = (ushort*)(pred + ND);    // 4 MB
    ushort* qlo   = qh + ND;
    ushort* kh    = qlo + ND;
    ushort* klo   = kh + ND;
    ushort* vbf   = klo + ND;
    ushort* vt    = vbf + ND;
    int* deg    = (int*)(vt + ND);
    int* counts = deg + N_;
    int* starts = counts + G_;
    int* pos    = starts + G_;
    int* offs   = pos + N_;
    int* cursor = offs + N_;
    int* eids   = cursor + N_;

    hipMemsetAsync(deg, 0, (size_t)(N_ + G_) * sizeof(int), stream);

    const int* src = edge_index;  // row 0 of (2, E)

    k_deg<<<E_ / 256, 256, 0, stream>>>(src, deg);
    k_counts<<<N_ / 256, 256, 0, stream>>>(batch, counts);
    k_scan<<<1, 64, 0, stream>>>(counts, starts);
    k_pos<<<N_ / 256, 256, 0, stream>>>(batch, starts, pos);
    k_scan_deg<<<1, 256, 0, stream>>>(deg, offs, cursor);
    k_fill_csr<<<E_ / 256, 256, 0, stream>>>(src, cursor, eids);
    k_build_dense<<<(N_ * 64) / 256, 256, 0, stream>>>(node_feature, centrality, edge_feature,
                                                       deg, offs, eids, batch, pos, dense);
    k_gemm_t<256, 1><<<dim3(128, 4), 256, 0, stream>>>(dense, Wq, nullptr,
                                                       nullptr, qh, qlo, nullptr);
    k_gemm_t<512, 2><<<dim3(128, 8), 256, 0, stream>>>(dense, Wkv, nullptr,
                                                       nullptr, kh, klo, vbf);
    k_conv_vt<<<dim3(256, 8), 256, 0, stream>>>(vbf, vt);
    k_attn_mfma<<<G_ * H_ * 8, 256, 0, stream>>>(qh, qlo, kh, klo, vt,
                                                 dist, dist_bias, counts, obuf);
    k_gemm_t<256, 0><<<dim3(128, 4), 256, 0, stream>>>(obuf, Wo, bo,
                                                       pred, nullptr, nullptr, nullptr);
    k_unpack<<<(N_ * 64) / 256, 256, 0, stream>>>(pred, batch, pos, out);
}

// Round 4
// 202.168 us; speedup vs baseline: 6.7885x; 1.4617x over previous
//
#include <hip/hip_runtime.h>
#include <hip/hip_bf16.h>
#include <math.h>

constexpr int N_   = 8192;
constexpr int D_   = 256;
constexpr int E_   = 131072;
constexpr int G_   = 16;
constexpr int MN_  = 512;
constexpr int H_   = 8;
constexpr int MAXG_= 512;

typedef __attribute__((ext_vector_type(8))) short short8v;   // 8 bf16 (4 VGPR)
typedef __attribute__((ext_vector_type(4))) float f32x4;     // MFMA C/D

// ---- bf16 helpers (RTNE via integer ops; input finite) ----
__device__ inline ushort f2bf(float f) {
    unsigned u = __float_as_uint(f);
    return (ushort)((u + 0x7FFFu + ((u >> 16) & 1u)) >> 16);
}
__device__ inline float bf2f(ushort h) { return __uint_as_float((unsigned)h << 16); }
__device__ inline unsigned cvt_pk_bf16(float lo, float hi) {
    unsigned r;
    asm("v_cvt_pk_bf16_f32 %0, %1, %2" : "=v"(r) : "v"(lo), "v"(hi));
    return r;
}

// ---------------- small index kernels ----------------
__global__ void k_deg(const int* __restrict__ src, int* __restrict__ deg) {
    int e = blockIdx.x * 256 + threadIdx.x;
    if (e < E_) atomicAdd(deg + src[e], 1);
}

// boundary detect on sorted batch: 16 uncontended writes total
__global__ void k_bounds(const int* __restrict__ batch, int* __restrict__ bstart) {
    int n = blockIdx.x * 256 + threadIdx.x;
    if (n >= N_) return;
    int g = batch[n];
    if (n == 0 || batch[n - 1] != g) bstart[g] = n;
}

// single-thread backward fill: starts/counts from bstart (empty graphs -> count 0)
__global__ void k_starts(const int* __restrict__ bstart, int* __restrict__ starts,
                         int* __restrict__ counts) {
    if (threadIdx.x != 0 || blockIdx.x != 0) return;
    int next = N_;
    for (int g = G_ - 1; g >= 0; --g) {
        int b = bstart[g];
        int s = (b >= 0) ? b : next;
        starts[g] = s;
        counts[g] = next - s;
        next = s;
    }
}

__global__ void k_scan_deg(const int* __restrict__ deg, int* __restrict__ offs,
                           int* __restrict__ cursor) {
    __shared__ int tpre[256];
    __shared__ int tsum[256];
    int t = threadIdx.x;
    int base = t * 32;
    int local[32];
    int s = 0;
#pragma unroll
    for (int k = 0; k < 32; ++k) { local[k] = deg[base + k]; s += local[k]; }
    tsum[t] = s;
    __syncthreads();
    if (t == 0) {
        int acc = 0;
        for (int i = 0; i < 256; ++i) { tpre[i] = acc; acc += tsum[i]; }
    }
    __syncthreads();
    int acc = tpre[t];
#pragma unroll
    for (int k = 0; k < 32; ++k) {
        offs[base + k] = acc;
        cursor[base + k] = acc;
        acc += local[k];
    }
}
__global__ void k_fill_csr(const int* __restrict__ src, int* __restrict__ cursor,
                           int* __restrict__ eids) {
    int e = blockIdx.x * 256 + threadIdx.x;
    if (e < E_) {
        int slot = atomicAdd(cursor + src[e], 1);
        eids[slot] = e;
    }
}

// ---------------- build dense batch (CSR edge gather fused) ----------------
__global__ void k_build_dense(const float* __restrict__ nf, const float* __restrict__ cent,
                              const float* __restrict__ ef, const int* __restrict__ deg,
                              const int* __restrict__ offs, const int* __restrict__ eids,
                              const int* __restrict__ batch, const int* __restrict__ starts,
                              float* __restrict__ dense) {
    int t  = blockIdx.x * 256 + threadIdx.x;
    int n  = t >> 6;
    int c4 = (t & 63) * 4;
    if (n >= N_) return;
    int g = batch[n];
    int row = g * MN_ + (n - starts[g]);
    int dn = deg[n];
    int dg = min(dn, MAXG_ - 1);
    float4 a = *(const float4*)(nf   + (size_t)n  * D_ + c4);
    float4 b = *(const float4*)(cent + (size_t)dg * D_ + c4);
    float4 o;
    o.x = a.x + b.x; o.y = a.y + b.y; o.z = a.z + b.z; o.w = a.w + b.w;
    int beg = offs[n], end = beg + dn;
    for (int idx = beg; idx < end; ++idx) {
        int e = eids[idx];
        float4 v = *(const float4*)(ef + (size_t)e * D_ + c4);
        o.x += v.x; o.y += v.y; o.z += v.z; o.w += v.w;
    }
    *(float4*)(dense + (size_t)row * D_ + c4) = o;
}

// ---------------- tiled fp32 GEMM: [8192 x 256] @ [256 x NC] ----------------
// MODE 0: float out + bias ; MODE 1: hi/lo bf16 out ; MODE 2: K->hi/lo, V->bf16
template<int NC, int MODE>
__global__ __launch_bounds__(256) void k_gemm_t(const float* __restrict__ A,
        const float* __restrict__ B, const float* __restrict__ bias,
        float* __restrict__ Cf, ushort* __restrict__ Hh, ushort* __restrict__ Ll,
        ushort* __restrict__ Vb) {
    __shared__ float As[64][20];
    __shared__ float Bs[16][64];
    int t = threadIdx.x;
    int mrow = blockIdx.x * 64;
    int ncol = blockIdx.y * 64;
    int tm = t >> 4, tn = t & 15;
    float acc[4][4] = {};
    for (int kc = 0; kc < 256; kc += 16) {
        {
            int r = t >> 2, k4 = (t & 3) * 4;
            *(float4*)&As[r][k4] = *(const float4*)(A + (size_t)(mrow + r) * 256 + kc + k4);
            int kk = t >> 4, c4 = (t & 15) * 4;
            *(float4*)&Bs[kk][c4] = *(const float4*)(B + (size_t)(kc + kk) * NC + ncol + c4);
        }
        __syncthreads();
#pragma unroll
        for (int k = 0; k < 16; ++k) {
            float4 b4 = *(float4*)&Bs[k][tn * 4];
#pragma unroll
            for (int u = 0; u < 4; ++u) {
                float a = As[tm * 4 + u][k];
                acc[u][0] += a * b4.x; acc[u][1] += a * b4.y;
                acc[u][2] += a * b4.z; acc[u][3] += a * b4.w;
            }
        }
        __syncthreads();
    }
    int row0 = mrow + tm * 4;
    int col0 = ncol + tn * 4;
#pragma unroll
    for (int u = 0; u < 4; ++u) {
        if (MODE == 0) {
            float4 o;
            o.x = acc[u][0] + bias[col0 + 0];
            o.y = acc[u][1] + bias[col0 + 1];
            o.z = acc[u][2] + bias[col0 + 2];
            o.w = acc[u][3] + bias[col0 + 3];
            *(float4*)(Cf + (size_t)(row0 + u) * NC + col0) = o;
        } else if (MODE == 1) {
            ushort4 hh, ll;
            float x;
            x = acc[u][0]; hh.x = f2bf(x); ll.x = f2bf(x - bf2f(hh.x));
            x = acc[u][1]; hh.y = f2bf(x); ll.y = f2bf(x - bf2f(hh.y));
            x = acc[u][2]; hh.z = f2bf(x); ll.z = f2bf(x - bf2f(hh.z));
            x = acc[u][3]; hh.w = f2bf(x); ll.w = f2bf(x - bf2f(hh.w));
            *(ushort4*)(Hh + (size_t)(row0 + u) * 256 + col0) = hh;
            *(ushort4*)(Ll + (size_t)(row0 + u) * 256 + col0) = ll;
        } else {
            if (ncol < 256) {
                ushort4 hh, ll;
                float x;
                x = acc[u][0]; hh.x = f2bf(x); ll.x = f2bf(x - bf2f(hh.x));
                x = acc[u][1]; hh.y = f2bf(x); ll.y = f2bf(x - bf2f(hh.y));
                x = acc[u][2]; hh.z = f2bf(x); ll.z = f2bf(x - bf2f(hh.z));
                x = acc[u][3]; hh.w = f2bf(x); ll.w = f2bf(x - bf2f(hh.w));
                *(ushort4*)(Hh + (size_t)(row0 + u) * 256 + col0) = hh;
                *(ushort4*)(Ll + (size_t)(row0 + u) * 256 + col0) = ll;
            } else {
                ushort4 vv;
                vv.x = f2bf(acc[u][0]); vv.y = f2bf(acc[u][1]);
                vv.z = f2bf(acc[u][2]); vv.w = f2bf(acc[u][3]);
                *(ushort4*)(Vb + (size_t)(row0 + u) * 256 + (col0 - 256)) = vv;
            }
        }
    }
}

// ---------------- V transpose: vbf[8192][256] -> vt[(g*8+h)*32+d][512] ----------------
__global__ __launch_bounds__(256) void k_conv_vt(const ushort* __restrict__ vbf,
                                                 ushort* __restrict__ vt) {
    __shared__ ushort tile[32][36];
    int bx = blockIdx.x;
    int h  = blockIdx.y;
    int t  = threadIdx.x;
    int r = t >> 3, c4 = (t & 7) * 4;
    *(ushort4*)&tile[r][c4] =
        *(const ushort4*)(vbf + (size_t)(bx * 32 + r) * 256 + h * 32 + c4);
    __syncthreads();
    int d = t >> 3, j4 = (t & 7) * 4;
    ushort4 o;
    o.x = tile[j4 + 0][d]; o.y = tile[j4 + 1][d];
    o.z = tile[j4 + 2][d]; o.w = tile[j4 + 3][d];
    int g = bx >> 4, jb = (bx & 15) * 32;
    *(ushort4*)(vt + ((size_t)(g * 8 + h) * 32 + d) * 512 + jb + j4) = o;
}

// ---------------- MFMA flash attention ----------------
__global__ __launch_bounds__(256) void k_attn_mfma(
    const ushort* __restrict__ qh, const ushort* __restrict__ qlo,
    const ushort* __restrict__ kh, const ushort* __restrict__ klo,
    const ushort* __restrict__ vt,
    const int* __restrict__ dist, const float* __restrict__ dist_bias,
    const int* __restrict__ counts, float* __restrict__ ob)
{
    int b  = blockIdx.x;
    int gh = b >> 3;                 // g*8 + h
    int g  = gh >> 3, h = gh & 7;
    int w    = threadIdx.x >> 6;
    int lane = threadIdx.x & 63;
    int ib   = (b & 7) * 64 + w * 16;
    int l15  = lane & 15, quad = lane >> 4;
    const float scale = 0.17677669529663687f;

    __shared__ float biasH[512];
    for (int idx = threadIdx.x; idx < 512; idx += 256) biasH[idx] = dist_bias[idx * 8 + h];
    __syncthreads();
    int cnt = counts[g];

    size_t qoff = ((size_t)(g * 512 + ib + l15)) * 256 + h * 32 + quad * 8;
    short8v qfh = *(const short8v*)(qh  + qoff);
    short8v qfl = *(const short8v*)(qlo + qoff);

    float m = -INFINITY, lsum = 0.f;
    f32x4 acc0 = {0.f, 0.f, 0.f, 0.f}, acc1 = {0.f, 0.f, 0.f, 0.f};

    const ushort* vbase = vt + ((size_t)gh * 32) * 512;
    const int* dbase = dist + ((size_t)(g * 512 + ib + l15)) * 512;
    size_t krowb = (size_t)(g * 512);

    for (int jb = 0; jb < 512; jb += 32) {
        float p[8];
        float mx = -INFINITY;
#pragma unroll
        for (int sub = 0; sub < 2; ++sub) {
            int j0 = jb + sub * 16;
            size_t koff = (krowb + j0 + l15) * 256 + h * 32 + quad * 8;
            short8v kfh = *(const short8v*)(kh  + koff);
            short8v kfl = *(const short8v*)(klo + koff);
            f32x4 c = {0.f, 0.f, 0.f, 0.f};
            c = __builtin_amdgcn_mfma_f32_16x16x32_bf16(kfl, qfh, c, 0, 0, 0);
            c = __builtin_amdgcn_mfma_f32_16x16x32_bf16(kfh, qfl, c, 0, 0, 0);
            c = __builtin_amdgcn_mfma_f32_16x16x32_bf16(kfh, qfh, c, 0, 0, 0);
            int4 d4 = *(const int4*)(dbase + j0 + quad * 4);
            const int* dr = (const int*)&d4;
#pragma unroll
            for (int r = 0; r < 4; ++r) {
                int dd = min(dr[r], MAXG_ - 1);
                float s = c[r] * scale + biasH[dd];
                bool valid = (j0 + quad * 4 + r) < cnt;
                s = valid ? s : -1e30f;
                p[sub * 4 + r] = s;
                mx = fmaxf(mx, s);
            }
        }
        mx = fmaxf(mx, __shfl_xor(mx, 16));
        mx = fmaxf(mx, __shfl_xor(mx, 32));
        float mnew = fmaxf(m, mx);
        float corr = __expf(m - mnew);
        m = mnew;
        float psum = 0.f;
#pragma unroll
        for (int u = 0; u < 8; ++u) {
            float pv = (p[u] > -1e29f) ? __expf(p[u] - m) : 0.f;
            p[u] = pv;
            psum += pv;
        }
        psum += __shfl_xor(psum, 16);
        psum += __shfl_xor(psum, 32);
        lsum = lsum * corr + psum;
#pragma unroll
        for (int r = 0; r < 4; ++r) {
            float cr = __shfl(corr, quad * 4 + r);
            acc0[r] *= cr; acc1[r] *= cr;
        }
        unsigned pk0A = cvt_pk_bf16(p[0], p[1]), pk1A = cvt_pk_bf16(p[2], p[3]);
        unsigned pk0B = cvt_pk_bf16(p[4], p[5]), pk1B = cvt_pk_bf16(p[6], p[7]);
        int srcA = l15 + 16 * (2 * (quad & 1));
        int srcB = srcA + 16;
        unsigned w0A = __shfl((int)pk0A, srcA), w1A = __shfl((int)pk1A, srcA);
        unsigned w2A = __shfl((int)pk0A, srcB), w3A = __shfl((int)pk1A, srcB);
        unsigned w0B = __shfl((int)pk0B, srcA), w1B = __shfl((int)pk1B, srcA);
        unsigned w2B = __shfl((int)pk0B, srcB), w3B = __shfl((int)pk1B, srcB);
        bool hiT = (quad >= 2);
        union { unsigned u[4]; short8v s; } pu;
        pu.u[0] = hiT ? w0B : w0A;
        pu.u[1] = hiT ? w1B : w1A;
        pu.u[2] = hiT ? w2B : w2A;
        pu.u[3] = hiT ? w3B : w3A;
        short8v pa = pu.s;
        short8v v0 = *(const short8v*)(vbase + (size_t)l15 * 512 + jb + quad * 8);
        short8v v1 = *(const short8v*)(vbase + (size_t)(l15 + 16) * 512 + jb + quad * 8);
        acc0 = __builtin_amdgcn_mfma_f32_16x16x32_bf16(pa, v0, acc0, 0, 0, 0);
        acc1 = __builtin_amdgcn_mfma_f32_16x16x32_bf16(pa, v1, acc1, 0, 0, 0);
    }
    float inv = lsum > 0.f ? 1.f / lsum : 0.f;
#pragma unroll
    for (int r = 0; r < 4; ++r) {
        float ir = __shfl(inv, quad * 4 + r);
        int i = ib + quad * 4 + r;
        float* orow = ob + ((size_t)(g * 512 + i)) * 256 + h * 32;
        orow[l15]      = acc0[r] * ir;
        orow[l15 + 16] = acc1[r] * ir;
    }
}

// ---------------- ragged unpack + last-graph zeroing ----------------
__global__ void k_unpack(const float* __restrict__ pred, const int* __restrict__ batch,
                         const int* __restrict__ starts, float* __restrict__ out) {
    int t = blockIdx.x * 256 + threadIdx.x;
    int n = t >> 6, c4 = (t & 63) * 4;
    if (n >= N_) return;
    int g = batch[n];
    int row = g * MN_ + (n - starts[g]);
    float4 v = make_float4(0.f, 0.f, 0.f, 0.f);
    if (g < G_ - 1) v = *(const float4*)(pred + (size_t)row * 256 + c4);
    *(float4*)(out + (size_t)n * 256 + c4) = v;
}

// ---------------- launch ----------------
extern "C" void kernel_launch(void* const* d_in, const int* in_sizes, int n_in,
                              void* d_out, int out_size, void* d_ws, size_t ws_size,
                              hipStream_t stream) {
    const float* node_feature = (const float*)d_in[0];
    const float* edge_feature = (const float*)d_in[1];
    const float* centrality   = (const float*)d_in[2];
    const float* dist_bias    = (const float*)d_in[3];
    const float* Wq           = (const float*)d_in[4];
    const float* Wkv          = (const float*)d_in[5];
    const float* Wo           = (const float*)d_in[6];
    const float* bo           = (const float*)d_in[7];
    const int*   edge_index   = (const int*)d_in[8];
    const int*   batch        = (const int*)d_in[9];
    const int*   dist         = (const int*)d_in[10];
    float* out = (float*)d_out;

    const size_t ND = (size_t)N_ * D_;
    float*  dense = (float*)d_ws;            // 8 MB
    float*  obuf  = dense + ND;              // 8 MB
    float*  pred  = obuf + ND;               // 8 MB
    ushort* qh    = (ushort*)(pred + ND);    // 4 MB each
    ushort* qlo   = qh + ND;
    ushort* kh    = qlo + ND;
    ushort* klo   = kh + ND;
    ushort* vbf   = klo + ND;
    ushort* vt    = vbf + ND;
    int* deg    = (int*)(vt + ND);           // N
    int* bstart = deg + N_;                  // G
    int* counts = bstart + G_;               // G
    int* starts = counts + G_;               // G
    int* offs   = starts + G_;               // N
    int* cursor = offs + N_;                 // N
    int* eids   = cursor + N_;               // E

    hipMemsetAsync(deg, 0, (size_t)N_ * sizeof(int), stream);
    hipMemsetAsync(bstart, 0xFF, (size_t)G_ * sizeof(int), stream);  // -1

    const int* src = edge_index;  // row 0 of (2, E)

    k_deg<<<E_ / 256, 256, 0, stream>>>(src, deg);
    k_bounds<<<N_ / 256, 256, 0, stream>>>(batch, bstart);
    k_starts<<<1, 64, 0, stream>>>(bstart, starts, counts);
    k_scan_deg<<<1, 256, 0, stream>>>(deg, offs, cursor);
    k_fill_csr<<<E_ / 256, 256, 0, stream>>>(src, cursor, eids);
    k_build_dense<<<(N_ * 64) / 256, 256, 0, stream>>>(node_feature, centrality, edge_feature,
                                                       deg, offs, eids, batch, starts, dense);
    k_gemm_t<256, 1><<<dim3(128, 4), 256, 0, stream>>>(dense, Wq, nullptr,
                                                       nullptr, qh, qlo, nullptr);
    k_gemm_t<512, 2><<<dim3(128, 8), 256, 0, stream>>>(dense, Wkv, nullptr,
                                                       nullptr, kh, klo, vbf);
    k_conv_vt<<<dim3(256, 8), 256, 0, stream>>>(vbf, vt);
    k_attn_mfma<<<G_ * H_ * 8, 256, 0, stream>>>(qh, qlo, kh, klo, vt,
                                                 dist, dist_bias, counts, obuf);
    k_gemm_t<256, 0><<<dim3(128, 4), 256, 0, stream>>>(obuf, Wo, bo,
                                                       pred, nullptr, nullptr, nullptr);
    k_unpack<<<(N_ * 64) / 256, 256, 0, stream>>>(pred, batch, starts, out);
}